// Round 1
// baseline (136.534 us; speedup 1.0000x reference)
//
#include <hip/hip_runtime.h>
#include <hip/hip_bf16.h>

// out[i] = y[i] * w[idx] + b[idx]
// idx = (t[i] << 10) | sum_j x[i][j] << (9 - j)   (t is the MSB)
// N = 2,000,000 rows, INPUT_DIM = 10, C = 2048.
// Memory-bound: ~104 MB total traffic -> ~16.5 us floor at 6.3 TB/s.
//
// v2: block-cooperative LDS staging of x. The old per-thread float2 loads
// were stride-40B address-divergent (40 lines/instr, 5 instrs re-touching
// the same lines = ~200 line-requests/wave vs 40 ideal). Staging with
// coalesced float4 loads issues each line exactly once (16 lines/instr).

#define INPUT_DIM 10
#define ROWS_PER_BLOCK 512            // 512 rows * 40 B = 20 KB LDS -> 8 blocks/CU

__global__ __launch_bounds__(256) void enc_kernel(
    const float* __restrict__ x,   // [N,10] binary 0/1
    const float* __restrict__ t,   // [N,1] binary 0/1
    const float* __restrict__ y,   // [N,1]
    const float* __restrict__ w,   // [2048]
    const float* __restrict__ b,   // [2048]
    float* __restrict__ out,       // [N,1]
    int n)
{
    __shared__ __align__(16) float xs[ROWS_PER_BLOCK * INPUT_DIM];  // 20480 B

    const int base = blockIdx.x * ROWS_PER_BLOCK;
    const int rows = (n - base < ROWS_PER_BLOCK) ? (n - base) : ROWS_PER_BLOCK;
    const int dw_valid = rows * INPUT_DIM;
    const float* gx = x + (size_t)base * INPUT_DIM;  // 20480*blockIdx bytes -> 16B aligned

    // Stage: 5120 dwords = 1280 float4; 256 threads * 5 float4 each.
    // Each instruction: consecutive lanes load consecutive float4 -> perfect
    // coalescing (1 KiB contiguous per wave per instruction).
#pragma unroll
    for (int k = 0; k < 5; ++k) {
        int d = (threadIdx.x + k * 256) * 4;
        if (d + 4 <= dw_valid) {
            *(float4*)&xs[d] = *(const float4*)&gx[d];
        } else if (d < dw_valid) {
            for (int j = d; j < dw_valid; ++j) xs[j] = gx[j];  // ragged tail (rare)
        }
    }
    __syncthreads();

    // Compute: thread handles rows tid and tid+256 -> y/t loads and out
    // stores stay fully coalesced per instruction.
    for (int r = threadIdx.x; r < rows; r += 256) {
        const int g = base + r;
        const float* xr = &xs[r * INPUT_DIM];

        // Balanced fmaf tree; all partial sums are small integers -> exact.
        float s0 = fmaf(xr[0], 512.f, t[g] * 1024.f);
        float s1 = fmaf(xr[1], 256.f, xr[2] * 128.f);
        float s2 = fmaf(xr[3],  64.f, xr[4] *  32.f);
        float s3 = fmaf(xr[5],  16.f, xr[6] *   8.f);
        float s4 = fmaf(xr[7],   4.f, xr[8] *   2.f);
        float s5 = s4 + xr[9];
        int idx = (int)((s0 + s1) + (s2 + s3) + s5);

        // w/b tables are 8 KB each -> L1-resident gather.
        out[g] = fmaf(y[g], w[idx], b[idx]);
    }
}

extern "C" void kernel_launch(void* const* d_in, const int* in_sizes, int n_in,
                              void* d_out, int out_size, void* d_ws, size_t ws_size,
                              hipStream_t stream) {
    const float* x = (const float*)d_in[0];
    const float* t = (const float*)d_in[1];
    const float* y = (const float*)d_in[2];
    const float* w = (const float*)d_in[3];
    const float* b = (const float*)d_in[4];
    float* out = (float*)d_out;

    int n = out_size;  // 2,000,000 rows
    int grid = (n + ROWS_PER_BLOCK - 1) / ROWS_PER_BLOCK;
    enc_kernel<<<grid, 256, 0, stream>>>(x, t, y, w, b, out, n);
}

// Round 2
// 136.119 us; speedup vs baseline: 1.0030x; 1.0030x over previous
//
#include <hip/hip_runtime.h>

// out[i] = y[i] * w[idx] + b[idx]
// idx = (t[i] << 10) | sum_j x[i][j] << (9 - j)   (t is the MSB)
// N = 2,000,000 rows, INPUT_DIM = 10, C = 2048.
//
// v3:
//  - (w,b) packed into an LDS float2 table: the two divergent 8KB-table L1
//    gathers per row (~50 serialized line-lookups per wave instr) become one
//    ds_read_b64 (LDS handles divergent gathers at ~4-8 cyc/wave).
//  - 2 rows per thread: an 80B row-pair = five 16B-aligned float4s, so the
//    LDS x-read is ds_read_b128 at stride 5 units; gcd(5,8)=1 spreads the 8
//    bank-groups evenly -> conflict-free b128 reads. float2 t/y loads and
//    float2 out store.
//  - idx bits via (__float_as_uint(f) >> 29) & 1  (exact for {0.0f, 1.0f};
//    &1 keeps idx in [0,2047] even for garbage tail lanes).
// LDS = 40KB x-stage + 16KB table = 56KB -> 2 blocks/CU x 8 waves = 16 waves/CU.

#define INPUT_DIM 10
#define THREADS 512
#define ROWS_PER_BLOCK 1024   // 2 rows per thread

__device__ __forceinline__ int fbit(float f) {
    return (int)((__float_as_uint(f) >> 29) & 1u);
}

__global__ __launch_bounds__(THREADS) void enc_kernel(
    const float* __restrict__ x,   // [N,10] binary 0/1
    const float* __restrict__ t,   // [N,1] binary 0/1
    const float* __restrict__ y,   // [N,1]
    const float* __restrict__ w,   // [2048]
    const float* __restrict__ b,   // [2048]
    float* __restrict__ out,       // [N,1]
    int n)
{
    __shared__ __align__(16) float  xs[ROWS_PER_BLOCK * INPUT_DIM]; // 40960 B
    __shared__ __align__(16) float2 wb[2048];                       // 16384 B

    const int tid  = threadIdx.x;
    const int base = blockIdx.x * ROWS_PER_BLOCK;
    const int rows = (n - base < ROWS_PER_BLOCK) ? (n - base) : ROWS_PER_BLOCK;
    const int dw_valid = rows * INPUT_DIM;
    const float* gx = x + (size_t)base * INPUT_DIM;  // 40960*blockIdx B -> 16B aligned

    // ---- (w,b) -> LDS float2 table: 2048 entries, 4 per thread ----
    {
        const int j = tid * 4;
        float4 w4 = *(const float4*)&w[j];
        float4 b4 = *(const float4*)&b[j];
        wb[j + 0] = make_float2(w4.x, b4.x);
        wb[j + 1] = make_float2(w4.y, b4.y);
        wb[j + 2] = make_float2(w4.z, b4.z);
        wb[j + 3] = make_float2(w4.w, b4.w);
    }

    // ---- x stage: 10240 dwords = 2560 float4 = 5 per thread, coalesced ----
#pragma unroll
    for (int k = 0; k < 5; ++k) {
        int d = (tid + k * THREADS) * 4;
        if (d + 4 <= dw_valid) {
            *(float4*)&xs[d] = *(const float4*)&gx[d];
        } else if (d < dw_valid) {
            for (int j = d; j < dw_valid; ++j) xs[j] = gx[j];  // ragged tail (rare)
        }
    }

    // Prefetch t/y (independent of LDS) so they overlap the barrier wait.
    const int r0 = 2 * tid;
    const int g0 = base + r0;
    const bool pair   = (r0 + 1 < rows);
    const bool single = (r0 < rows) && !pair;
    float2 tv = make_float2(0.f, 0.f), yv = make_float2(0.f, 0.f);
    if (pair) {
        tv = *(const float2*)&t[g0];
        yv = *(const float2*)&y[g0];
    } else if (single) {
        tv.x = t[g0];
        yv.x = y[g0];
    }

    __syncthreads();

    if (r0 >= rows) return;

    // Row-pair = 80B, 16B-aligned: five ds_read_b128, conflict-free (stride 5).
    const float4* xp = (const float4*)&xs[r0 * INPUT_DIM];
    float4 q0 = xp[0], q1 = xp[1], q2 = xp[2], q3 = xp[3], q4 = xp[4];

    int idx0 = (fbit(tv.x) << 10)
             | (fbit(q0.x) << 9) | (fbit(q0.y) << 8)
             | (fbit(q0.z) << 7) | (fbit(q0.w) << 6)
             | (fbit(q1.x) << 5) | (fbit(q1.y) << 4)
             | (fbit(q1.z) << 3) | (fbit(q1.w) << 2)
             | (fbit(q2.x) << 1) |  fbit(q2.y);

    if (pair) {
        int idx1 = (fbit(tv.y) << 10)
                 | (fbit(q2.z) << 9) | (fbit(q2.w) << 8)
                 | (fbit(q3.x) << 7) | (fbit(q3.y) << 6)
                 | (fbit(q3.z) << 5) | (fbit(q3.w) << 4)
                 | (fbit(q4.x) << 3) | (fbit(q4.y) << 2)
                 | (fbit(q4.z) << 1) |  fbit(q4.w);
        float2 c0 = wb[idx0];
        float2 c1 = wb[idx1];
        *(float2*)&out[g0] = make_float2(fmaf(yv.x, c0.x, c0.y),
                                         fmaf(yv.y, c1.x, c1.y));
    } else {
        float2 c0 = wb[idx0];
        out[g0] = fmaf(yv.x, c0.x, c0.y);
    }
}

extern "C" void kernel_launch(void* const* d_in, const int* in_sizes, int n_in,
                              void* d_out, int out_size, void* d_ws, size_t ws_size,
                              hipStream_t stream) {
    const float* x = (const float*)d_in[0];
    const float* t = (const float*)d_in[1];
    const float* y = (const float*)d_in[2];
    const float* w = (const float*)d_in[3];
    const float* b = (const float*)d_in[4];
    float* out = (float*)d_out;

    int n = out_size;  // 2,000,000 rows
    int grid = (n + ROWS_PER_BLOCK - 1) / ROWS_PER_BLOCK;
    enc_kernel<<<grid, THREADS, 0, stream>>>(x, t, y, w, b, out, n);
}

// Round 3
// 134.226 us; speedup vs baseline: 1.0172x; 1.0141x over previous
//
#include <hip/hip_runtime.h>

// out[i] = y[i] * w[idx] + b[idx]
// idx = (t[i] << 10) | sum_j x[i][j] << (9 - j)   (t is the MSB)
// N = 2,000,000 rows, INPUT_DIM = 10, C = 2048.
//
// v4: wave-ballot bit packing.
//  - x loaded dword-coalesced (lane l, instr k -> element 64k+l): each load
//    instruction touches exactly 2 cache lines -> 40 line-touches per 128-row
//    tile (the ideal). No LDS staging of x, no staging barrier.
//  - __ballot(v != 0) packs 64 consecutive binary x-elements into one 64-bit
//    mask; 20 ballots cover a 128-row tile (1280 bits). Lane 0 parks them in
//    LDS; each lane funnel-shifts its 20-bit window (rows 2l, 2l+1).
//  - idx = (__brev(10-bit field) >> 22) | t<<10  (bit-reverse = MSB-first
//    weights in one instruction).
//  - (w,b) as 16 KB LDS float2 table (one ds_read_b64 per row).
// LDS 17 KB, ~48 VGPR -> 8 blocks/CU (full occupancy). Every non-HBM pipe
// is >5x under the ~15 us HBM floor by construction.

#define INPUT_DIM 10
#define THREADS 256
#define WAVES_PB 4
#define ROWS_PER_WAVE 128
#define ROWS_PER_BLOCK 512   // WAVES_PB * ROWS_PER_WAVE

__device__ __forceinline__ uint32_t fbitu(uint32_t u) { return (u >> 29) & 1u; }

__global__ __launch_bounds__(THREADS) void enc_kernel(
    const float* __restrict__ x,   // [N,10] binary 0/1
    const float* __restrict__ t,   // [N,1] binary 0/1
    const float* __restrict__ y,   // [N,1]
    const float* __restrict__ w,   // [2048]
    const float* __restrict__ b,   // [2048]
    float* __restrict__ out,       // [N,1]
    int n)
{
    __shared__ __align__(16) float2 wb[2048];            // 16384 B
    __shared__ unsigned long long bal[WAVES_PB][21];     // 672 B (entry 20 = pad)

    const int tid = threadIdx.x;

    // ---- (w,b) -> LDS float2 table: 8 entries per thread, float4 loads ----
    {
        const int j = tid * 8;
        const float4 w0 = *(const float4*)&w[j];
        const float4 w1 = *(const float4*)&w[j + 4];
        const float4 b0 = *(const float4*)&b[j];
        const float4 b1 = *(const float4*)&b[j + 4];
        wb[j + 0] = make_float2(w0.x, b0.x);
        wb[j + 1] = make_float2(w0.y, b0.y);
        wb[j + 2] = make_float2(w0.z, b0.z);
        wb[j + 3] = make_float2(w0.w, b0.w);
        wb[j + 4] = make_float2(w1.x, b1.x);
        wb[j + 5] = make_float2(w1.y, b1.y);
        wb[j + 6] = make_float2(w1.z, b1.z);
        wb[j + 7] = make_float2(w1.w, b1.w);
    }
    __syncthreads();

    const int wave = tid >> 6;
    const int lane = tid & 63;
    const long long rowbase =
        (long long)blockIdx.x * ROWS_PER_BLOCK + (long long)wave * ROWS_PER_WAVE;
    if (rowbase >= n) return;

    if (rowbase + ROWS_PER_WAVE <= (long long)n) {
        // ---------- fast path: full 128-row wave tile ----------
        const uint32_t* xu = (const uint32_t*)x + rowbase * INPUT_DIM;

        uint32_t v[20];
#pragma unroll
        for (int k = 0; k < 20; ++k) v[k] = xu[k * 64 + lane];  // coalesced dwords

        const int g = (int)rowbase + 2 * lane;      // this lane's row pair
        const float2 tv = *(const float2*)&t[g];
        const float2 yv = *(const float2*)&y[g];

        unsigned long long s[20];
#pragma unroll
        for (int k = 0; k < 20; ++k) s[k] = __ballot(v[k] != 0u);

        if (lane == 0) {
#pragma unroll
            for (int k = 0; k < 20; ++k) bal[wave][k] = s[k];
            bal[wave][20] = 0ull;
        }
        // Wave-internal LDS ordering (DS ops complete in issue order within a
        // wave); the memory-clobbered wait stops any compiler reordering.
        asm volatile("s_waitcnt lgkmcnt(0)" ::: "memory");

        // 20-bit window at bit offset 20*lane of the 1280-bit tile string.
        const int bo = 20 * lane;
        const int j0 = bo >> 6;
        const int sh = bo & 63;
        unsigned long long lo = bal[wave][j0];
        unsigned long long hi = bal[wave][j0 + 1];   // j0+1 <= 20 (pad)
        unsigned long long wnd = lo >> sh;
        if (sh) wnd |= hi << (64 - sh);

        const uint32_t f0 = (uint32_t)wnd & 0x3FFu;          // row 2l, bits LSB=col0
        const uint32_t f1 = (uint32_t)(wnd >> 10) & 0x3FFu;  // row 2l+1
        const int idx0 = (int)((__brev(f0) >> 22) | (fbitu(__float_as_uint(tv.x)) << 10));
        const int idx1 = (int)((__brev(f1) >> 22) | (fbitu(__float_as_uint(tv.y)) << 10));

        const float2 c0 = wb[idx0];
        const float2 c1 = wb[idx1];
        *(float2*)&out[g] = make_float2(fmaf(yv.x, c0.x, c0.y),
                                        fmaf(yv.y, c1.x, c1.y));
    } else {
        // ---------- generic tail (never taken for n = 2,000,000) ----------
        for (long long r = rowbase + lane; r < (long long)n; r += 64) {
            const uint32_t* xr = (const uint32_t*)x + r * INPUT_DIM;
            uint32_t id = fbitu(__float_as_uint(t[r])) << 10;
#pragma unroll
            for (int j = 0; j < INPUT_DIM; ++j) id |= fbitu(xr[j]) << (9 - j);
            const float2 c = wb[id];
            out[r] = fmaf(y[r], c.x, c.y);
        }
    }
}

extern "C" void kernel_launch(void* const* d_in, const int* in_sizes, int n_in,
                              void* d_out, int out_size, void* d_ws, size_t ws_size,
                              hipStream_t stream) {
    const float* x = (const float*)d_in[0];
    const float* t = (const float*)d_in[1];
    const float* y = (const float*)d_in[2];
    const float* w = (const float*)d_in[3];
    const float* b = (const float*)d_in[4];
    float* out = (float*)d_out;

    int n = out_size;  // 2,000,000 rows
    int grid = (n + ROWS_PER_BLOCK - 1) / ROWS_PER_BLOCK;
    enc_kernel<<<grid, THREADS, 0, stream>>>(x, t, y, w, b, out, n);
}